// Round 1
// 427.035 us; speedup vs baseline: 1.0021x; 1.0021x over previous
//
#include <hip/hip_runtime.h>

// AttnDecoder single step, MI355X. ALL float tensors are float32 (per reference);
// y_i is int32. Output: [log_softmax (V), h_new (H)] float32, concatenated.
//
// Memory-bound: W_o (206 MB f32) dominates -> wave-per-row matvec at full HBM BW.
// Roofline: ~248 MB mandatory reads / 6.3 TB/s ~= 39 us floor.
// Measured decomposition: dur_us ~= 3x120us harness ws-poison fills + ~68us kernels.
// This version: 4 dispatches (attn folded into GRU kernel), 2-row unrolled logits.

#define V_SIZE 50257
#define HDIM   1024
#define LDIM   20

__device__ __forceinline__ float wave_sum(float v) {
#pragma unroll
    for (int o = 32; o > 0; o >>= 1) v += __shfl_down(v, o, 64);
    return v;  // lane 0 holds the sum
}

// ---------------- K1: d[e] = dot(W_t[e,:], h) + b_t[e] + emb[y][e] ----------------
__global__ void __launch_bounds__(256)
k_dvec(const float* __restrict__ Wt, const float* __restrict__ bt,
       const float* __restrict__ hvec, const float* __restrict__ emb,
       const int* __restrict__ y, float* __restrict__ dvec) {
    int e = blockIdx.x, t = threadIdx.x;
    float4 w  = ((const float4*)(Wt + (size_t)e * HDIM))[t];
    float4 hh = ((const float4*)hvec)[t];
    float s = w.x*hh.x + w.y*hh.y + w.z*hh.z + w.w*hh.w;
    s = wave_sum(s);
    __shared__ float part[4];
    if ((t & 63) == 0) part[t >> 6] = s;
    __syncthreads();
    if (t == 0) {
        float tot = part[0] + part[1] + part[2] + part[3];
        int yy = y[0];
        tot += bt[e] + emb[(size_t)yy * HDIM + e];
        dvec[e] = tot;
    }
}

// ---------------- K2: fused attention + GRU. Each block redundantly computes
//                  softmax(d @ cnn_a) and c = a @ cnn_c^T (L2-resident reads),
//                  then GRU row j as before. ----------------
__global__ void __launch_bounds__(256)
k_gru(const float* __restrict__ Wih, const float* __restrict__ Whh,
      const float* __restrict__ bih, const float* __restrict__ bhh,
      const float* __restrict__ hvec, const float* __restrict__ emb,
      const int* __restrict__ y, const float* __restrict__ dvec,
      const float* __restrict__ cnn_a, const float* __restrict__ cnn_c,
      float* __restrict__ hnew, float* __restrict__ out_h) {
    int j = blockIdx.x, t = threadIdx.x;

    // ---- phase A: scores[l] = sum_e d[e]*cnn_a[e,l] (thread t covers e = 4t..4t+3)
    float p[LDIM];
    {
        float4 d4 = ((const float4*)dvec)[t];
        const float* ar = cnn_a + (size_t)t * 4 * LDIM;
#pragma unroll
        for (int l = 0; l < LDIM; ++l)
            p[l] = d4.x * ar[l] + d4.y * ar[LDIM + l]
                 + d4.z * ar[2 * LDIM + l] + d4.w * ar[3 * LDIM + l];
    }
#pragma unroll
    for (int l = 0; l < LDIM; ++l) p[l] = wave_sum(p[l]);
    __shared__ float spart[4 * LDIM];
    if ((t & 63) == 0) {
        int w = t >> 6;
#pragma unroll
        for (int l = 0; l < LDIM; ++l) spart[w * LDIM + l] = p[l];
    }
    __syncthreads();
    __shared__ float aw[LDIM];
    if (t == 0) {
        float sc[LDIM];
        for (int l = 0; l < LDIM; ++l)
            sc[l] = spart[l] + spart[LDIM + l] + spart[2 * LDIM + l] + spart[3 * LDIM + l];
        float m = sc[0];
        for (int l = 1; l < LDIM; ++l) m = fmaxf(m, sc[l]);
        float ss = 0.f;
        for (int l = 0; l < LDIM; ++l) { sc[l] = expf(sc[l] - m); ss += sc[l]; }
        float inv = 1.0f / ss;
        for (int l = 0; l < LDIM; ++l) aw[l] = sc[l] * inv;
    }
    __syncthreads();
    // ---- context c[e] = sum_l aw[l]*cnn_c[e,l], into LDS
    __shared__ float csh[1024];
    {
        const float* cr = cnn_c + (size_t)t * 4 * LDIM;
        float c0 = 0.f, c1 = 0.f, c2 = 0.f, c3 = 0.f;
#pragma unroll
        for (int l = 0; l < LDIM; ++l) {
            float a = aw[l];
            c0 += a * cr[l];
            c1 += a * cr[LDIM + l];
            c2 += a * cr[2 * LDIM + l];
            c3 += a * cr[3 * LDIM + l];
        }
        csh[4 * t + 0] = c0; csh[4 * t + 1] = c1;
        csh[4 * t + 2] = c2; csh[4 * t + 3] = c3;
    }
    __syncthreads();

    // ---- phase B: GRU row j (identical math/order to previous version)
    int base = t * 8;                          // col range [base, base+8) of 2048
    float xs[8];
    if (t < 128) {                             // x[0:1024] = emb[y]  (wave-uniform branch)
        int yy = y[0];
        const float* xsrc = emb + (size_t)yy * HDIM + base;
        float4 a = ((const float4*)xsrc)[0], b = ((const float4*)xsrc)[1];
        xs[0]=a.x; xs[1]=a.y; xs[2]=a.z; xs[3]=a.w;
        xs[4]=b.x; xs[5]=b.y; xs[6]=b.z; xs[7]=b.w;
    } else {                                   // x[1024:2048] = c (from LDS)
        int cb = base - 1024;
#pragma unroll
        for (int i = 0; i < 8; ++i) xs[i] = csh[cb + i];
    }
    float4 hq = ((const float4*)hvec)[t];

    float acc[6];
#pragma unroll
    for (int g = 0; g < 3; ++g) {
        const float* wr = Wih + (size_t)(j + g * 1024) * 2048 + base;
        float4 a = ((const float4*)wr)[0], b = ((const float4*)wr)[1];
        acc[g] = a.x*xs[0] + a.y*xs[1] + a.z*xs[2] + a.w*xs[3]
               + b.x*xs[4] + b.y*xs[5] + b.z*xs[6] + b.w*xs[7];
    }
#pragma unroll
    for (int g = 0; g < 3; ++g) {
        float4 q = ((const float4*)(Whh + (size_t)(j + g * 1024) * 1024))[t];
        acc[3 + g] = q.x*hq.x + q.y*hq.y + q.z*hq.z + q.w*hq.w;
    }
    __shared__ float part[4][6];
#pragma unroll
    for (int i = 0; i < 6; ++i) {
        float s = wave_sum(acc[i]);
        if ((t & 63) == 0) part[t >> 6][i] = s;
    }
    __syncthreads();
    if (t == 0) {
        float v[6];
#pragma unroll
        for (int i = 0; i < 6; ++i) v[i] = part[0][i] + part[1][i] + part[2][i] + part[3][i];
        float ir  = v[0] + bih[j];
        float iz  = v[1] + bih[j + 1024];
        float in_ = v[2] + bih[j + 2048];
        float hr  = v[3] + bhh[j];
        float hz  = v[4] + bhh[j + 1024];
        float hn  = v[5] + bhh[j + 2048];
        float r = 1.0f / (1.0f + expf(-(ir + hr)));
        float z = 1.0f / (1.0f + expf(-(iz + hz)));
        float n = tanhf(in_ + r * hn);
        float hj = hvec[j];
        float hv = (1.0f - z) * n + z * hj;
        hnew[j] = hv;
        out_h[j] = hv;                         // gru_hidden output (f32)
    }
}

// ---------------- K3: logits[v] = dot(W_o[v,:], h_new) + b_o[v]; online (m,s);
//                  2 rows / wave-iteration, block-combined partials ----------------
__global__ void __launch_bounds__(256)
k_logits(const float* __restrict__ Wo, const float* __restrict__ bo,
         const float* __restrict__ hnew, float* __restrict__ logits,
         float* __restrict__ pm, float* __restrict__ ps) {
    int t = threadIdx.x;
    int lane = t & 63, w = t >> 6;
    int wave_id = blockIdx.x * 4 + w;          // 0..4095
    const int nwaves = 4096;
    float h[16];                               // h_new[lane*16 .. +15] in regs, loaded once
    const float4* hv4 = (const float4*)hnew;
#pragma unroll
    for (int i = 0; i < 4; ++i) {
        float4 q = hv4[lane * 4 + i];
        h[i*4+0]=q.x; h[i*4+1]=q.y; h[i*4+2]=q.z; h[i*4+3]=q.w;
    }
    float m = -1e30f, s = 0.0f;
    for (int v0 = wave_id * 2; v0 < V_SIZE; v0 += 2 * nwaves) {
        const float4* rA = (const float4*)(Wo + (size_t)v0 * HDIM);
        float4 q0 = rA[lane*4+0], q1 = rA[lane*4+1], q2 = rA[lane*4+2], q3 = rA[lane*4+3];
        float a = q0.x*h[0]  + q0.y*h[1]  + q0.z*h[2]  + q0.w*h[3]
                + q1.x*h[4]  + q1.y*h[5]  + q1.z*h[6]  + q1.w*h[7]
                + q2.x*h[8]  + q2.y*h[9]  + q2.z*h[10] + q2.w*h[11]
                + q3.x*h[12] + q3.y*h[13] + q3.z*h[14] + q3.w*h[15];
        int v1 = v0 + 1;
        bool hasB = (v1 < V_SIZE);
        float b = 0.0f;
        if (hasB) {
            const float4* rB = (const float4*)(Wo + (size_t)v1 * HDIM);
            float4 r0 = rB[lane*4+0], r1 = rB[lane*4+1], r2 = rB[lane*4+2], r3 = rB[lane*4+3];
            b = r0.x*h[0]  + r0.y*h[1]  + r0.z*h[2]  + r0.w*h[3]
              + r1.x*h[4]  + r1.y*h[5]  + r1.z*h[6]  + r1.w*h[7]
              + r2.x*h[8]  + r2.y*h[9]  + r2.z*h[10] + r2.w*h[11]
              + r3.x*h[12] + r3.y*h[13] + r3.z*h[14] + r3.w*h[15];
        }
        a = wave_sum(a);
        b = wave_sum(b);                       // independent chains -> ILP
        if (lane == 0) {
            float lv = a + bo[v0];
            logits[v0] = lv;
            float mn = fmaxf(m, lv);
            s = s * expf(m - mn) + expf(lv - mn);
            m = mn;
            if (hasB) {
                float lv1 = b + bo[v1];
                logits[v1] = lv1;
                float mn1 = fmaxf(m, lv1);
                s = s * expf(m - mn1) + expf(lv1 - mn1);
                m = mn1;
            }
        }
    }
    // combine the block's 4 wave partials -> one (m,s) per block
    __shared__ float sm[4], ssv[4];
    if (lane == 0) { sm[w] = m; ssv[w] = s; }
    __syncthreads();
    if (t == 0) {
        float M = sm[0], S = ssv[0];
#pragma unroll
        for (int i = 1; i < 4; ++i) {
            float mn = fmaxf(M, sm[i]);
            S = S * expf(M - mn) + ssv[i] * expf(sm[i] - mn);
            M = mn;
        }
        pm[blockIdx.x] = M; ps[blockIdx.x] = S;
    }
}

// ---------------- K4: logZ from partials (redundant per block), write log_softmax ----------------
__global__ void __launch_bounds__(256)
k_out(const float* __restrict__ logits, const float* __restrict__ pm,
      const float* __restrict__ ps, float* __restrict__ out, int nparts) {
    int t = threadIdx.x;
    float m = -1e30f, s = 0.0f;
    for (int i = t; i < nparts; i += 256) {
        float m2 = pm[i], s2 = ps[i];
        float mn = fmaxf(m, m2);
        s = s * expf(m - mn) + s2 * expf(m2 - mn);
        m = mn;
    }
#pragma unroll
    for (int o = 32; o > 0; o >>= 1) {
        float m2 = __shfl_down(m, o, 64);
        float s2 = __shfl_down(s, o, 64);
        float mn = fmaxf(m, m2);
        s = s * expf(m - mn) + s2 * expf(m2 - mn);
        m = mn;
    }
    __shared__ float sm[4], ssv[4];
    if ((t & 63) == 0) { sm[t >> 6] = m; ssv[t >> 6] = s; }
    __syncthreads();
    __shared__ float logZ;
    if (t == 0) {
        float M = sm[0], S = ssv[0];
        for (int i = 1; i < 4; ++i) {
            float mn = fmaxf(M, sm[i]);
            S = S * expf(M - mn) + ssv[i] * expf(sm[i] - mn);
            M = mn;
        }
        logZ = M + logf(S);
    }
    __syncthreads();
    float lz = logZ;
    for (int v = blockIdx.x * 256 + t; v < V_SIZE; v += gridDim.x * 256)
        out[v] = logits[v] - lz;
}

extern "C" void kernel_launch(void* const* d_in, const int* in_sizes, int n_in,
                              void* d_out, int out_size, void* d_ws, size_t ws_size,
                              hipStream_t stream) {
    const int*   y     = (const int*)d_in[0];
    const float* h_i   = (const float*)d_in[1];
    const float* cnn_a = (const float*)d_in[2];
    const float* cnn_c = (const float*)d_in[3];
    const float* emb   = (const float*)d_in[4];
    const float* W_t   = (const float*)d_in[5];
    const float* b_t   = (const float*)d_in[6];
    const float* W_ih  = (const float*)d_in[7];
    const float* W_hh  = (const float*)d_in[8];
    const float* b_ih  = (const float*)d_in[9];
    const float* b_hh  = (const float*)d_in[10];
    const float* W_o   = (const float*)d_in[11];
    const float* b_o   = (const float*)d_in[12];
    float*       out   = (float*)d_out;

    // ws layout (f32): [0,1024) d | [2048,3072) h_new |
    //                  [4096, 4096+50257) logits | [54528,+1024) pm | [58624,+1024) ps
    float* ws     = (float*)d_ws;
    float* dvec   = ws;
    float* hnew   = ws + 2048;
    float* logits = ws + 4096;
    float* pm     = ws + 54528;
    float* ps     = ws + 58624;

    k_dvec<<<1024, 256, 0, stream>>>(W_t, b_t, h_i, emb, y, dvec);
    k_gru<<<1024, 256, 0, stream>>>(W_ih, W_hh, b_ih, b_hh, h_i, emb, y, dvec,
                                    cnn_a, cnn_c, hnew, out + V_SIZE);
    k_logits<<<1024, 256, 0, stream>>>(W_o, b_o, hnew, logits, pm, ps);
    k_out<<<256, 256, 0, stream>>>(logits, pm, ps, out, 1024);
}